// Round 7
// baseline (283.447 us; speedup 1.0000x reference)
//
#include <hip/hip_runtime.h>

#define HH 20
#define WW 20
#define TT 96
#define BB 64
#define SIG 306
#define NFC 17
#define TSTRIDE 264    // feat per-t stride: 16pix*16ch + 8 (bank de-alias)
#define CHUNK 16
#define NCHUNK 6
#define XT 199         // xs per-t stride
#define KTOT 122400
#define KSLAB 120
#define NSLAB 2        // 240 K per mlp1 block
#define NKBLK 510      // 510 * 240 = 122400

typedef float float4u __attribute__((ext_vector_type(4), aligned(4)));

// ---------------------------------------------------------------------------
// Kernel 1: conv + signature -> sig workspace.
// Block = 256 thr (4 waves) = one (b, 4x4-pixel tile). Grid 64*25 = 1600.
// Phase-2 telescoped: accv' = sum (f(t)+f(t-1)) * (f(t)-f(t-1));
// true core = 0.5*accv' - f0_i*lvl1_j (corrected once at the write).
// Chunk 0 peeled so every phase-2 loop has constant bounds (full unroll).
// ---------------------------------------------------------------------------
__global__ __launch_bounds__(256) void sig_kernel(
    const float* __restrict__ x,    // (64,96,4,20,20)
    const float* __restrict__ cw,   // (12,4,3,3)
    float* __restrict__ sig)        // (64,122400)
{
  __shared__ __align__(16) float feat[15 * TSTRIDE + 256 + 8];  // 16.9 KB
  __shared__ __align__(16) float xs[CHUNK * XT];                // 12.7 KB
  __shared__ __align__(16) float wlds[12 * 48];                 // [k][ci][dy][4]

  const int tid = threadIdx.x;
  const int blk = blockIdx.x;
  const int b = blk / 25;
  const int tile = blk % 25;
  const int th4 = (tile / 5) * 4, tw4 = (tile % 5) * 4;
  const float* xb0 = x + (size_t)b * TT * 1600;

  // ---- stage conv weights to LDS (bias dropped: signature bias-invariant) ----
  #pragma unroll
  for (int r = 0; r < 3; r++) {
    int idx = r * 256 + tid;
    if (idx < 576) {
      int k = idx / 48, rem = idx % 48;
      int ci = rem / 12, r2 = rem % 12, dy = r2 >> 2, dx = r2 & 3;
      wlds[idx] = (dx < 3) ? cw[k * 36 + ci * 9 + dy * 3 + dx] : 0.f;
    }
  }

  // ---- staging precompute: 2304 = 9*256 halo values per chunk ----
  int g_off[9], l_off[9];   // g_off = -1 for OOB (SAME padding -> 0)
  #pragma unroll
  for (int r = 0; r < 9; r++) {
    int idx = r * 256 + tid;
    int t = idx / 144, q = idx % 144;
    int ci = q / 36, pos = q % 36, row = pos / 6, col = pos % 6;
    int gr = th4 - 1 + row, gc = tw4 - 1 + col;
    bool valid = (gr >= 0 && gr < HH && gc >= 0 && gc < WW);
    g_off[r] = valid ? (t * 1600 + ci * 400 + gr * WW + gc) : -1;
    l_off[r] = t * XT + ci * 48 + row * 8 + col;
  }

  // ---- conv mapping: lane = pix*16 + tt ----
  const int cpix = tid >> 4, ctt = tid & 15;
  const int cpy = cpix >> 2, cpx = cpix & 3;

  // ---- phase-2 mapping: lane = pix*16 + (it*4 + jt) ----
  const int p2 = tid >> 4;
  const int rr = tid & 15, it = rr >> 2, jt = rr & 3;
  const int i0 = it * 4, j0 = jt * 4;

  float accv[4][4];
  float f0a[4], f0b[4], pa[4], pb[4], fsum[4];
  #pragma unroll
  for (int i = 0; i < 4; i++) {
    #pragma unroll
    for (int j = 0; j < 4; j++) accv[i][j] = 0.f;
  }

  auto stage = [&](int chunk) {
    const float* xbc = xb0 + (size_t)chunk * CHUNK * 1600;
    float rg[9];
    #pragma unroll
    for (int r = 0; r < 9; r++)
      rg[r] = (g_off[r] >= 0) ? xbc[g_off[r]] : 0.f;
    #pragma unroll
    for (int r = 0; r < 9; r++) xs[l_off[r]] = rg[r];
  };

  auto conv = [&]() {
    float win[4][9];
    const int wb2 = ctt * XT;
    #pragma unroll
    for (int ci = 0; ci < 4; ci++)
      #pragma unroll
      for (int dy = 0; dy < 3; dy++)
        #pragma unroll
        for (int dxx = 0; dxx < 3; dxx++)
          win[ci][dy * 3 + dxx] = xs[wb2 + ci * 48 + (cpy + dy) * 8 + (cpx + dxx)];

    float fk[12];
    #pragma unroll
    for (int k = 0; k < 12; k++) {
      float a = 0.f;
      #pragma unroll
      for (int ci = 0; ci < 4; ci++) {
        #pragma unroll
        for (int dy = 0; dy < 3; dy++) {
          const float4 w4 = *reinterpret_cast<const float4*>(
              &wlds[k * 48 + ci * 12 + dy * 4]);
          a += win[ci][dy * 3 + 0] * w4.x + win[ci][dy * 3 + 1] * w4.y +
               win[ci][dy * 3 + 2] * w4.z;
        }
      }
      fk[k] = a;
    }
    float* fr = &feat[ctt * TSTRIDE + cpix * 16];
    *reinterpret_cast<float4*>(fr + 0)  = make_float4(fk[0], fk[1], fk[2], fk[3]);
    *reinterpret_cast<float4*>(fr + 4)  = make_float4(fk[4], fk[5], fk[6], fk[7]);
    *reinterpret_cast<float4*>(fr + 8)  = make_float4(fk[8], fk[9], fk[10], fk[11]);
    *reinterpret_cast<float4*>(fr + 12) = make_float4(win[0][4], win[1][4], win[2][4], win[3][4]);
  };

  auto p2step = [&](int tt) {
    const float* row = &feat[tt * TSTRIDE + p2 * 16];
    const float4 a4 = *reinterpret_cast<const float4*>(row + i0);
    const float4 b4 = *reinterpret_cast<const float4*>(row + j0);
    float fa[4] = {a4.x, a4.y, a4.z, a4.w};
    float fb[4] = {b4.x, b4.y, b4.z, b4.w};
    float sa[4], db[4];
    #pragma unroll
    for (int i = 0; i < 4; i++) { sa[i] = fa[i] + pa[i]; db[i] = fb[i] - pb[i]; }
    #pragma unroll
    for (int i = 0; i < 4; i++)
      #pragma unroll
      for (int j = 0; j < 4; j++) accv[i][j] += sa[i] * db[j];
    #pragma unroll
    for (int i = 0; i < 4; i++) { fsum[i] += fa[i]; pa[i] = fa[i]; pb[i] = fb[i]; }
  };

  // ===== chunk 0 (peeled: row-0 init, then tt = 1..15 constant-bound) =====
  stage(0);
  __syncthreads();
  conv();
  __syncthreads();
  {
    const float* r0 = &feat[p2 * 16];
    const float4 a4 = *reinterpret_cast<const float4*>(r0 + i0);
    const float4 b4 = *reinterpret_cast<const float4*>(r0 + j0);
    f0a[0] = a4.x; f0a[1] = a4.y; f0a[2] = a4.z; f0a[3] = a4.w;
    f0b[0] = b4.x; f0b[1] = b4.y; f0b[2] = b4.z; f0b[3] = b4.w;
    #pragma unroll
    for (int i = 0; i < 4; i++) { pa[i] = f0a[i]; pb[i] = f0b[i]; fsum[i] = f0a[i]; }
  }
  #pragma unroll
  for (int tt = 1; tt < CHUNK; tt++) p2step(tt);

  // ===== chunks 1..5 =====
  for (int chunk = 1; chunk < NCHUNK; chunk++) {
    __syncthreads();   // phase-2 done -> xs/feat may be rewritten
    stage(chunk);
    __syncthreads();
    conv();
    __syncthreads();
    #pragma unroll
    for (int tt = 0; tt < CHUNK; tt++) p2step(tt);
  }

  // ===== write sig: corrected core + analytic tch row/col/corner + lvl1 =====
  {
    const int ph = th4 + (p2 >> 2), pw = tw4 + (p2 & 3);
    float* sb = sig + (size_t)b * KTOT + (size_t)(ph * WW + pw) * SIG;
    float lv1b[4];
    #pragma unroll
    for (int j = 0; j < 4; j++) lv1b[j] = pb[j] - f0b[j];
    #pragma unroll
    for (int ii = 0; ii < 4; ii++) {
      float4u v;
      #pragma unroll
      for (int jj = 0; jj < 4; jj++)
        v[jj] = 0.5f * accv[ii][jj] - f0a[ii] * lv1b[jj];
      *reinterpret_cast<float4u*>(sb + NFC + (i0 + ii) * NFC + j0) = v;
    }
    if (jt == 0) {
      #pragma unroll
      for (int ii = 0; ii < 4; ii++) {
        const int c = i0 + ii;
        const float f0 = f0a[ii], f95 = pa[ii], fs = fsum[ii];
        sb[c] = f95 - f0;                                            // lvl1
        sb[NFC + c * NFC + 16] = (fs - 95.5f * f0 - 0.5f * f95) * (1.f / 95.f);
        sb[NFC + 16 * NFC + c] = (95.5f * f95 + 0.5f * f0 - fs) * (1.f / 95.f);
      }
      if (it == 0) { sb[16] = 1.0f; sb[NFC + 16 * NFC + 16] = 0.5f; }
    }
  }
}

// ---------------------------------------------------------------------------
// Kernel 2: MLP-1 K-split GEMM. 510 blocks x 240-K slabs.
// ATOMIC=false: partials -> part[(blk,64,32)]; ATOMIC=true: fallback.
// ---------------------------------------------------------------------------
template<bool ATOMIC>
__global__ __launch_bounds__(256) void mlp1_gemm(
    const float* __restrict__ sig, const float* __restrict__ w1,
    float* __restrict__ part)
{
  __shared__ __align__(16) float ldsT[KSLAB * 68];   // [k][b]
  __shared__ __align__(16) float wls[KSLAB * 32];    // [k][n]
  const int tid = threadIdx.x;
  const int n = tid & 31, bq = tid >> 5;
  const int k0 = blockIdx.x * (KSLAB * NSLAB);

  float a8[8];
  #pragma unroll
  for (int i = 0; i < 8; i++) a8[i] = 0.f;

  for (int s = 0; s < NSLAB; s++) {
    const int ks = k0 + s * KSLAB;
    __syncthreads();   // protect LDS reuse across slabs
    #pragma unroll
    for (int r = 0; r < 30; r++) {             // 64*120/256
      int idx = r * 256 + tid;
      int b = idx / KSLAB, kk = idx % KSLAB;
      ldsT[kk * 68 + b] = sig[(size_t)b * KTOT + ks + kk];
    }
    #pragma unroll
    for (int r = 0; r < 15; r++) {             // 120*32/256
      int idx = r * 256 + tid;
      wls[idx] = w1[(size_t)ks * 32 + idx];
    }
    __syncthreads();

    #pragma unroll 4
    for (int kk = 0; kk < KSLAB; kk++) {
      const float w = wls[kk * 32 + n];
      const float4 s0 = *reinterpret_cast<const float4*>(&ldsT[kk * 68 + bq * 8]);
      const float4 s1 = *reinterpret_cast<const float4*>(&ldsT[kk * 68 + bq * 8 + 4]);
      a8[0] += s0.x * w; a8[1] += s0.y * w; a8[2] += s0.z * w; a8[3] += s0.w * w;
      a8[4] += s1.x * w; a8[5] += s1.y * w; a8[6] += s1.z * w; a8[7] += s1.w * w;
    }
  }

  if (ATOMIC) {
    #pragma unroll
    for (int i = 0; i < 8; i++)
      atomicAdd(&part[(bq * 8 + i) * 32 + n], a8[i]);
  } else {
    const size_t pb = (size_t)blockIdx.x * (BB * 32);
    #pragma unroll
    for (int i = 0; i < 8; i++)
      part[pb + (bq * 8 + i) * 32 + n] = a8[i];
  }
}

// ---------------------------------------------------------------------------
// Kernel 3: partial-reduce + MLP layers 2-4. 8 blocks x 256 thr.
// ---------------------------------------------------------------------------
__global__ __launch_bounds__(256) void mlp_tail(
    const float* __restrict__ part, int npart, const float* __restrict__ b1,
    const float* __restrict__ w2, const float* __restrict__ b2,
    const float* __restrict__ w3, const float* __restrict__ b3,
    const float* __restrict__ w4, const float* __restrict__ b4,
    float* __restrict__ out)
{
  const int tid = threadIdx.x;
  const int n = tid & 31;
  const int b = blockIdx.x * 8 + (tid >> 5);
  const int lane = tid & 63;
  const int grp = lane & 32;

  float s = 0.f;
  #pragma unroll 4
  for (int p = 0; p < npart; p++)
    s += part[(size_t)p * (BB * 32) + b * 32 + n];

  float h = fmaxf(s + b1[n], 0.f);

  float v = b2[n];
  #pragma unroll
  for (int k = 0; k < 32; k++)
    v += __shfl(h, grp + k, 64) * w2[k * 32 + n];
  h = fmaxf(v, 0.f);

  v = b3[n];
  #pragma unroll
  for (int k = 0; k < 32; k++)
    v += __shfl(h, grp + k, 64) * w3[k * 32 + n];
  h = fmaxf(v, 0.f);

  float p = h * w4[n];
  #pragma unroll
  for (int o = 16; o >= 1; o >>= 1) p += __shfl_xor(p, o, 64);
  if (n == 0) out[b] = p + b4[0];
}

extern "C" void kernel_launch(void* const* d_in, const int* in_sizes, int n_in,
                              void* d_out, int out_size, void* d_ws, size_t ws_size,
                              hipStream_t stream) {
  const float* x  = (const float*)d_in[0];
  const float* cw = (const float*)d_in[1];
  const float* w1 = (const float*)d_in[3];
  const float* b1 = (const float*)d_in[4];
  const float* w2 = (const float*)d_in[5];
  const float* b2 = (const float*)d_in[6];
  const float* w3 = (const float*)d_in[7];
  const float* b3 = (const float*)d_in[8];
  const float* w4 = (const float*)d_in[9];
  const float* b4 = (const float*)d_in[10];
  float* out = (float*)d_out;

  const size_t sig_bytes  = (size_t)BB * KTOT * sizeof(float);        // 31.3 MB
  const size_t part_bytes = (size_t)NKBLK * BB * 32 * sizeof(float);  // 4.18 MB
  float* sigm = (float*)d_ws;

  sig_kernel<<<dim3(1600), dim3(256), 0, stream>>>(x, cw, sigm);

  if (ws_size >= sig_bytes + part_bytes) {
    float* part = (float*)((char*)d_ws + sig_bytes);
    mlp1_gemm<false><<<dim3(NKBLK), dim3(256), 0, stream>>>(sigm, w1, part);
    mlp_tail<<<dim3(8), dim3(256), 0, stream>>>(part, NKBLK, b1, w2, b2, w3, b3, w4, b4, out);
  } else {
    float* acc = (float*)((char*)d_ws + sig_bytes);   // 8 KB
    hipMemsetAsync(acc, 0, BB * 32 * sizeof(float), stream);
    mlp1_gemm<true><<<dim3(NKBLK), dim3(256), 0, stream>>>(sigm, w1, acc);
    mlp_tail<<<dim3(8), dim3(256), 0, stream>>>(acc, 1, b1, w2, b2, w3, b3, w4, b4, out);
  }
}

// Round 8
// 250.674 us; speedup vs baseline: 1.1307x; 1.1307x over previous
//
#include <hip/hip_runtime.h>

#define HH 20
#define WW 20
#define TT 96
#define BB 64
#define SIG 306
#define NFC 17
#define TSTRIDE 264    // feat per-t stride: 16pix*16ch + 8 (bank de-alias)
#define CHUNK 16
#define NCHUNK 6
#define XT 199         // xs per-t stride
#define KTOT 122400
#define KSLAB 120
#define NSLAB 4        // 480 K per mlp1 block
#define NKBLK 255      // 255 * 480 = 122400
#define LDT 66         // ldsT row stride (bank-stride 2 on staging writes)

typedef float float4u __attribute__((ext_vector_type(4), aligned(4)));

// ---------------------------------------------------------------------------
// Kernel 1: conv + signature -> sig workspace. (FROZEN from round 7: 144 us)
// Block = 256 thr (4 waves) = one (b, 4x4-pixel tile). Grid 64*25 = 1600.
// Phase-2 telescoped: accv' = sum (f(t)+f(t-1)) * (f(t)-f(t-1));
// true core = 0.5*accv' - f0_i*lvl1_j (corrected once at the write).
// ---------------------------------------------------------------------------
__global__ __launch_bounds__(256) void sig_kernel(
    const float* __restrict__ x,    // (64,96,4,20,20)
    const float* __restrict__ cw,   // (12,4,3,3)
    float* __restrict__ sig)        // (64,122400)
{
  __shared__ __align__(16) float feat[15 * TSTRIDE + 256 + 8];
  __shared__ __align__(16) float xs[CHUNK * XT];
  __shared__ __align__(16) float wlds[12 * 48];   // [k][ci][dy][4]

  const int tid = threadIdx.x;
  const int blk = blockIdx.x;
  const int b = blk / 25;
  const int tile = blk % 25;
  const int th4 = (tile / 5) * 4, tw4 = (tile % 5) * 4;
  const float* xb0 = x + (size_t)b * TT * 1600;

  // ---- stage conv weights (bias dropped: signature bias-invariant) ----
  #pragma unroll
  for (int r = 0; r < 3; r++) {
    int idx = r * 256 + tid;
    if (idx < 576) {
      int k = idx / 48, rem = idx % 48;
      int ci = rem / 12, r2 = rem % 12, dy = r2 >> 2, dx = r2 & 3;
      wlds[idx] = (dx < 3) ? cw[k * 36 + ci * 9 + dy * 3 + dx] : 0.f;
    }
  }

  // ---- staging precompute: 2304 = 9*256 halo values per chunk ----
  int g_off[9], l_off[9];
  #pragma unroll
  for (int r = 0; r < 9; r++) {
    int idx = r * 256 + tid;
    int t = idx / 144, q = idx % 144;
    int ci = q / 36, pos = q % 36, row = pos / 6, col = pos % 6;
    int gr = th4 - 1 + row, gc = tw4 - 1 + col;
    bool valid = (gr >= 0 && gr < HH && gc >= 0 && gc < WW);
    g_off[r] = valid ? (t * 1600 + ci * 400 + gr * WW + gc) : -1;
    l_off[r] = t * XT + ci * 48 + row * 8 + col;
  }

  const int cpix = tid >> 4, ctt = tid & 15;
  const int cpy = cpix >> 2, cpx = cpix & 3;

  const int p2 = tid >> 4;
  const int rr = tid & 15, it = rr >> 2, jt = rr & 3;
  const int i0 = it * 4, j0 = jt * 4;

  float accv[4][4];
  float f0a[4], f0b[4], pa[4], pb[4], fsum[4];
  #pragma unroll
  for (int i = 0; i < 4; i++) {
    #pragma unroll
    for (int j = 0; j < 4; j++) accv[i][j] = 0.f;
  }

  auto stage = [&](int chunk) {
    const float* xbc = xb0 + (size_t)chunk * CHUNK * 1600;
    float rg[9];
    #pragma unroll
    for (int r = 0; r < 9; r++)
      rg[r] = (g_off[r] >= 0) ? xbc[g_off[r]] : 0.f;
    #pragma unroll
    for (int r = 0; r < 9; r++) xs[l_off[r]] = rg[r];
  };

  auto conv = [&]() {
    float win[4][9];
    const int wb2 = ctt * XT;
    #pragma unroll
    for (int ci = 0; ci < 4; ci++)
      #pragma unroll
      for (int dy = 0; dy < 3; dy++)
        #pragma unroll
        for (int dxx = 0; dxx < 3; dxx++)
          win[ci][dy * 3 + dxx] = xs[wb2 + ci * 48 + (cpy + dy) * 8 + (cpx + dxx)];

    float fk[12];
    #pragma unroll
    for (int k = 0; k < 12; k++) {
      float a = 0.f;
      #pragma unroll
      for (int ci = 0; ci < 4; ci++) {
        #pragma unroll
        for (int dy = 0; dy < 3; dy++) {
          const float4 w4 = *reinterpret_cast<const float4*>(
              &wlds[k * 48 + ci * 12 + dy * 4]);
          a += win[ci][dy * 3 + 0] * w4.x + win[ci][dy * 3 + 1] * w4.y +
               win[ci][dy * 3 + 2] * w4.z;
        }
      }
      fk[k] = a;
    }
    float* fr = &feat[ctt * TSTRIDE + cpix * 16];
    *reinterpret_cast<float4*>(fr + 0)  = make_float4(fk[0], fk[1], fk[2], fk[3]);
    *reinterpret_cast<float4*>(fr + 4)  = make_float4(fk[4], fk[5], fk[6], fk[7]);
    *reinterpret_cast<float4*>(fr + 8)  = make_float4(fk[8], fk[9], fk[10], fk[11]);
    *reinterpret_cast<float4*>(fr + 12) = make_float4(win[0][4], win[1][4], win[2][4], win[3][4]);
  };

  auto p2step = [&](int tt) {
    const float* row = &feat[tt * TSTRIDE + p2 * 16];
    const float4 a4 = *reinterpret_cast<const float4*>(row + i0);
    const float4 b4 = *reinterpret_cast<const float4*>(row + j0);
    float fa[4] = {a4.x, a4.y, a4.z, a4.w};
    float fb[4] = {b4.x, b4.y, b4.z, b4.w};
    float sa[4], db[4];
    #pragma unroll
    for (int i = 0; i < 4; i++) { sa[i] = fa[i] + pa[i]; db[i] = fb[i] - pb[i]; }
    #pragma unroll
    for (int i = 0; i < 4; i++)
      #pragma unroll
      for (int j = 0; j < 4; j++) accv[i][j] += sa[i] * db[j];
    #pragma unroll
    for (int i = 0; i < 4; i++) { fsum[i] += fa[i]; pa[i] = fa[i]; pb[i] = fb[i]; }
  };

  // ===== chunk 0 (peeled) =====
  stage(0);
  __syncthreads();
  conv();
  __syncthreads();
  {
    const float* r0 = &feat[p2 * 16];
    const float4 a4 = *reinterpret_cast<const float4*>(r0 + i0);
    const float4 b4 = *reinterpret_cast<const float4*>(r0 + j0);
    f0a[0] = a4.x; f0a[1] = a4.y; f0a[2] = a4.z; f0a[3] = a4.w;
    f0b[0] = b4.x; f0b[1] = b4.y; f0b[2] = b4.z; f0b[3] = b4.w;
    #pragma unroll
    for (int i = 0; i < 4; i++) { pa[i] = f0a[i]; pb[i] = f0b[i]; fsum[i] = f0a[i]; }
  }
  #pragma unroll
  for (int tt = 1; tt < CHUNK; tt++) p2step(tt);

  // ===== chunks 1..5 =====
  for (int chunk = 1; chunk < NCHUNK; chunk++) {
    __syncthreads();
    stage(chunk);
    __syncthreads();
    conv();
    __syncthreads();
    #pragma unroll
    for (int tt = 0; tt < CHUNK; tt++) p2step(tt);
  }

  // ===== write sig =====
  {
    const int ph = th4 + (p2 >> 2), pw = tw4 + (p2 & 3);
    float* sb = sig + (size_t)b * KTOT + (size_t)(ph * WW + pw) * SIG;
    float lv1b[4];
    #pragma unroll
    for (int j = 0; j < 4; j++) lv1b[j] = pb[j] - f0b[j];
    #pragma unroll
    for (int ii = 0; ii < 4; ii++) {
      float4u v;
      #pragma unroll
      for (int jj = 0; jj < 4; jj++)
        v[jj] = 0.5f * accv[ii][jj] - f0a[ii] * lv1b[jj];
      *reinterpret_cast<float4u*>(sb + NFC + (i0 + ii) * NFC + j0) = v;
    }
    if (jt == 0) {
      #pragma unroll
      for (int ii = 0; ii < 4; ii++) {
        const int c = i0 + ii;
        const float f0 = f0a[ii], f95 = pa[ii], fs = fsum[ii];
        sb[c] = f95 - f0;                                            // lvl1
        sb[NFC + c * NFC + 16] = (fs - 95.5f * f0 - 0.5f * f95) * (1.f / 95.f);
        sb[NFC + 16 * NFC + c] = (95.5f * f95 + 0.5f * f0 - fs) * (1.f / 95.f);
      }
      if (it == 0) { sb[16] = 1.0f; sb[NFC + 16 * NFC + 16] = 0.5f; }
    }
  }
}

// ---------------------------------------------------------------------------
// Kernel 2: MLP-1 K-split GEMM. 255 blocks x 480-K (4 slabs of 120).
// ATOMIC=false: partials -> part[(blk,64,32)]; ATOMIC=true: fallback.
// ---------------------------------------------------------------------------
template<bool ATOMIC>
__global__ __launch_bounds__(256) void mlp1_gemm(
    const float* __restrict__ sig, const float* __restrict__ w1,
    float* __restrict__ part)
{
  __shared__ __align__(16) float ldsT[KSLAB * LDT];  // [k][b] 31.7 KB
  __shared__ __align__(16) float wls[KSLAB * 32];    // [k][n] 15.4 KB
  const int tid = threadIdx.x;
  const int n = tid & 31, bq = tid >> 5;
  const int k0 = blockIdx.x * (KSLAB * NSLAB);

  float a8[8];
  #pragma unroll
  for (int i = 0; i < 8; i++) a8[i] = 0.f;

  for (int s = 0; s < NSLAB; s++) {
    const int ks = k0 + s * KSLAB;
    __syncthreads();   // protect LDS reuse across slabs
    #pragma unroll
    for (int r = 0; r < 30; r++) {             // 64*120/256
      int idx = r * 256 + tid;
      int b = idx / KSLAB, kk = idx % KSLAB;
      ldsT[kk * LDT + b] = sig[(size_t)b * KTOT + ks + kk];
    }
    #pragma unroll
    for (int r = 0; r < 15; r++) {             // 120*32/256
      int idx = r * 256 + tid;
      wls[idx] = w1[(size_t)ks * 32 + idx];
    }
    __syncthreads();

    #pragma unroll 4
    for (int kk = 0; kk < KSLAB; kk++) {
      const float w = wls[kk * 32 + n];
      const float4 s0 = *reinterpret_cast<const float4*>(&ldsT[kk * LDT + bq * 8]);
      const float4 s1 = *reinterpret_cast<const float4*>(&ldsT[kk * LDT + bq * 8 + 4]);
      a8[0] += s0.x * w; a8[1] += s0.y * w; a8[2] += s0.z * w; a8[3] += s0.w * w;
      a8[4] += s1.x * w; a8[5] += s1.y * w; a8[6] += s1.z * w; a8[7] += s1.w * w;
    }
  }

  if (ATOMIC) {
    #pragma unroll
    for (int i = 0; i < 8; i++)
      atomicAdd(&part[(bq * 8 + i) * 32 + n], a8[i]);
  } else {
    const size_t pb = (size_t)blockIdx.x * (BB * 32);
    #pragma unroll
    for (int i = 0; i < 8; i++)
      part[pb + (bq * 8 + i) * 32 + n] = a8[i];
  }
}

// ---------------------------------------------------------------------------
// Kernel 3: partial-reduce + MLP layers 2-4. 64 blocks (one per b) x 256 thr.
// Thread (s=tid>>5, n=tid&31) sums partials p = s, s+8, ... ; LDS tree over s;
// then lanes 0..31 of wave 0 run the 3-layer MLP via shuffle broadcast.
// ---------------------------------------------------------------------------
__global__ __launch_bounds__(256) void mlp_tail(
    const float* __restrict__ part, int npart, const float* __restrict__ b1,
    const float* __restrict__ w2, const float* __restrict__ b2,
    const float* __restrict__ w3, const float* __restrict__ b3,
    const float* __restrict__ w4, const float* __restrict__ b4,
    float* __restrict__ out)
{
  __shared__ float red[8][33];
  const int tid = threadIdx.x;
  const int n = tid & 31;
  const int s = tid >> 5;            // 0..7
  const int b = blockIdx.x;

  float sum = 0.f;
  #pragma unroll 8
  for (int p = s; p < npart; p += 8)
    sum += part[(size_t)p * (BB * 32) + b * 32 + n];
  red[s][n] = sum;
  __syncthreads();

  if (tid < 32) {
    float acc = red[0][n];
    #pragma unroll
    for (int q = 1; q < 8; q++) acc += red[q][n];

    float h = fmaxf(acc + b1[n], 0.f);

    float v = b2[n];
    #pragma unroll
    for (int k = 0; k < 32; k++)
      v += __shfl(h, k, 64) * w2[k * 32 + n];
    h = fmaxf(v, 0.f);

    v = b3[n];
    #pragma unroll
    for (int k = 0; k < 32; k++)
      v += __shfl(h, k, 64) * w3[k * 32 + n];
    h = fmaxf(v, 0.f);

    float p = h * w4[n];
    #pragma unroll
    for (int o = 16; o >= 1; o >>= 1) p += __shfl_xor(p, o, 64);
    if (n == 0) out[b] = p + b4[0];
  }
}

extern "C" void kernel_launch(void* const* d_in, const int* in_sizes, int n_in,
                              void* d_out, int out_size, void* d_ws, size_t ws_size,
                              hipStream_t stream) {
  const float* x  = (const float*)d_in[0];
  const float* cw = (const float*)d_in[1];
  const float* w1 = (const float*)d_in[3];
  const float* b1 = (const float*)d_in[4];
  const float* w2 = (const float*)d_in[5];
  const float* b2 = (const float*)d_in[6];
  const float* w3 = (const float*)d_in[7];
  const float* b3 = (const float*)d_in[8];
  const float* w4 = (const float*)d_in[9];
  const float* b4 = (const float*)d_in[10];
  float* out = (float*)d_out;

  const size_t sig_bytes  = (size_t)BB * KTOT * sizeof(float);        // 31.3 MB
  const size_t part_bytes = (size_t)NKBLK * BB * 32 * sizeof(float);  // 2.09 MB
  float* sigm = (float*)d_ws;

  sig_kernel<<<dim3(1600), dim3(256), 0, stream>>>(x, cw, sigm);

  if (ws_size >= sig_bytes + part_bytes) {
    float* part = (float*)((char*)d_ws + sig_bytes);
    mlp1_gemm<false><<<dim3(NKBLK), dim3(256), 0, stream>>>(sigm, w1, part);
    mlp_tail<<<dim3(64), dim3(256), 0, stream>>>(part, NKBLK, b1, w2, b2, w3, b3, w4, b4, out);
  } else {
    float* acc = (float*)((char*)d_ws + sig_bytes);   // 8 KB
    hipMemsetAsync(acc, 0, BB * 32 * sizeof(float), stream);
    mlp1_gemm<true><<<dim3(NKBLK), dim3(256), 0, stream>>>(sigm, w1, acc);
    mlp_tail<<<dim3(64), dim3(256), 0, stream>>>(acc, 1, b1, w2, b2, w3, b3, w4, b4, out);
  }
}